// Round 8
// baseline (198.680 us; speedup 1.0000x reference)
//
#include <hip/hip_runtime.h>
#include <hip/hip_bf16.h>

// B=2, N=2048, D=1024, H=16, DH=64. f32 in / f32 out, bf16 MFMA internally.

typedef unsigned short u16;
typedef unsigned int u32;
typedef __bf16 bf16x8 __attribute__((ext_vector_type(8)));
typedef float  f32x4  __attribute__((ext_vector_type(4)));
typedef unsigned short u16x4 __attribute__((ext_vector_type(4)));
typedef unsigned int u32x4 __attribute__((ext_vector_type(4)));

#define DEV __device__ __forceinline__

DEV float exp2fast(float x) { return __builtin_amdgcn_exp2f(x); }  // v_exp_f32

DEV u16 f2bf(float f) {
  unsigned u = __builtin_bit_cast(unsigned, f);
  return (u16)((u + 0x7FFFu + ((u >> 16) & 1u)) >> 16);  // RNE
}

DEV f32x4 mfma16(bf16x8 a, bf16x8 b, f32x4 c) {
  return __builtin_amdgcn_mfma_f32_16x16x32_bf16(a, b, c, 0, 0, 0);
}

template <typename T>
DEV void gload16(const T* g, T* l) {  // global -> LDS, 16B per lane, dest = base + lane*16
  __builtin_amdgcn_global_load_lds((__attribute__((address_space(1))) void*)g,
                                   (__attribute__((address_space(3))) void*)l, 16, 0, 0);
}

// ---------------- prep kernels ----------------

__global__ __launch_bounds__(256) void cvt_x(const float* __restrict__ x,
                                             u16* __restrict__ xb) {
  int idx = (blockIdx.x * 256 + threadIdx.x) * 4;
  float4 v = *(const float4*)(x + idx);
  u16x4 u = { f2bf(v.x), f2bf(v.y), f2bf(v.z), f2bf(v.w) };
  *(u16x4*)(xb + idx) = u;
}

// merged weight transpose: bx<48 -> w_qkv (C=3072, q-scale on cols<1024),
// else w_out (C=1024). dst[c][r] = bf16(src[r][c] * scale), R=1024.
__global__ __launch_bounds__(256) void wtrans_all(const float* __restrict__ wq,
                                                  const float* __restrict__ wo,
                                                  u16* __restrict__ dq,
                                                  u16* __restrict__ dow) {
  __shared__ u16 T[64][72];
  const int tid = threadIdx.x;
  int bx = blockIdx.x;
  const float* src; u16* dst; int C, sl;
  if (bx < 48) { src = wq; dst = dq; C = 3072; sl = 1024; }
  else         { bx -= 48; src = wo; dst = dow; C = 1024; sl = 0; }
  const int c0 = bx * 64, r0 = blockIdx.y * 64;
  const int cl = tid & 63;
  // q-scale folded: 1/sqrt(64) * log2(e)  (softmax runs in exp2 domain)
  const float scale = (c0 + cl < sl) ? 0.125f * 1.4426950408889634f : 1.0f;
#pragma unroll
  for (int i = 0; i < 16; ++i) {
    int r = (tid >> 6) * 16 + i;
    T[cl][r] = f2bf(src[(size_t)(r0 + r) * C + c0 + cl] * scale);
  }
  __syncthreads();
#pragma unroll
  for (int i = 0; i < 16; ++i) {
    int cc = (tid >> 6) * 16 + i;
    dst[(size_t)(c0 + cc) * 1024 + r0 + cl] = T[cc][cl];
  }
}

// ---------------- GEMM1: [4096,1024] x [3072,1024]^T, 128x128 tile ----------
// Q/K cols (n0<2048) -> qk[row][2048]; V cols -> vt[b][h][d][n] directly.
// 1D grid, bijective XCD swizzle: newid = (id&7)*cpx + (id>>3).

__global__ __launch_bounds__(256) void gemm_bf16(const u16* __restrict__ A,
                                                 const u16* __restrict__ Bt,
                                                 u16* __restrict__ qk,
                                                 u16* __restrict__ vt,
                                                 int nx, int cpx) {
  __shared__ __align__(16) u16 lA[128 * 64];
  __shared__ __align__(16) u16 lB[128 * 64];
  const int tid = threadIdx.x;
  const int lane = tid & 63, w = tid >> 6;
  const int g = lane >> 4, r16 = lane & 15;
  const int wm = w >> 1, wn = w & 1;
  const int id = (int)blockIdx.x;
  const int newid = (id & 7) * cpx + (id >> 3);  // nwg % 8 == 0
  const int m0 = (newid / nx) * 128, n0 = (newid % nx) * 128;

  const f32x4 z4 = {0.f, 0.f, 0.f, 0.f};
  f32x4 acc[4][4];
#pragma unroll
  for (int m = 0; m < 4; ++m)
#pragma unroll
    for (int n = 0; n < 4; ++n) acc[m][n] = z4;

  for (int kt = 0; kt < 16; ++kt) {
    const int kbase = kt * 64;
#pragma unroll
    for (int issue = 0; issue < 4; ++issue) {
      int i = issue * 256 + tid;
      int r = i >> 3, jp = (i & 7) ^ (r & 7);  // swizzled source chunk
      gload16(A + (size_t)(m0 + r) * 1024 + kbase + jp * 8,
              lA + (size_t)(issue * 256 + (tid & ~63)) * 8);
      gload16(Bt + (size_t)(n0 + r) * 1024 + kbase + jp * 8,
              lB + (size_t)(issue * 256 + (tid & ~63)) * 8);
    }
    __syncthreads();
#pragma unroll
    for (int kk = 0; kk < 2; ++kk) {
      bf16x8 a[4], b[4];
#pragma unroll
      for (int m = 0; m < 4; ++m) {
        int row = wm * 64 + m * 16 + r16;
        int off = row * 128 + ((kk * 64 + g * 16) ^ ((r16 & 7) << 4));
        a[m] = *(const bf16x8*)((const char*)lA + off);
      }
#pragma unroll
      for (int n = 0; n < 4; ++n) {
        int row = wn * 64 + n * 16 + r16;
        int off = row * 128 + ((kk * 64 + g * 16) ^ ((r16 & 7) << 4));
        b[n] = *(const bf16x8*)((const char*)lB + off);
      }
      __builtin_amdgcn_s_setprio(1);
#pragma unroll
      for (int m = 0; m < 4; ++m)
#pragma unroll
        for (int n = 0; n < 4; ++n) acc[m][n] = mfma16(a[m], b[n], acc[m][n]);
      __builtin_amdgcn_s_setprio(0);
    }
    __syncthreads();
  }
  if (n0 < 2048) {  // Q/K -> qk[row][2048]
#pragma unroll
    for (int m = 0; m < 4; ++m)
#pragma unroll
      for (int n = 0; n < 4; ++n) {
        int col = n0 + wn * 64 + n * 16 + r16;
#pragma unroll
        for (int j = 0; j < 4; ++j) {
          int row = m0 + wm * 64 + m * 16 + g * 4 + j;
          qk[(size_t)row * 2048 + col] = f2bf(acc[m][n][j]);
        }
      }
  } else {  // V -> vt[(b*16+h)*64+d][2048] packed 4-row u16x4 stores
#pragma unroll
    for (int m = 0; m < 4; ++m) {
      int row0 = m0 + wm * 64 + m * 16 + g * 4;  // j = 0..3 consecutive rows
      int b = row0 >> 11, nn0 = row0 & 2047;
#pragma unroll
      for (int n = 0; n < 4; ++n) {
        int hcol = n0 - 2048 + wn * 64 + n * 16 + r16;
        int h = hcol >> 6, d = hcol & 63;
        u16x4 pk = { f2bf(acc[m][n][0]), f2bf(acc[m][n][1]),
                     f2bf(acc[m][n][2]), f2bf(acc[m][n][3]) };
        *(u16x4*)(vt + (size_t)((b * 16 + h) * 64 + d) * 2048 + nn0) = pk;
      }
    }
  }
}

// ---------------- GEMM2: 64x64 tile (4 blocks/CU) --------------------------

__global__ __launch_bounds__(256) void gemm64(const u16* __restrict__ A,
                                              const u16* __restrict__ Bt,
                                              float* __restrict__ Cf,
                                              int N, int nx, int cpx) {
  __shared__ __align__(16) u16 lA[64 * 64];
  __shared__ __align__(16) u16 lB[64 * 64];
  const int tid = threadIdx.x;
  const int lane = tid & 63, w = tid >> 6;
  const int g = lane >> 4, r16 = lane & 15;
  const int wm = w >> 1, wn = w & 1;
  const int id = (int)blockIdx.x;
  const int newid = (id & 7) * cpx + (id >> 3);
  const int m0 = (newid / nx) * 64, n0 = (newid % nx) * 64;

  const f32x4 z4 = {0.f, 0.f, 0.f, 0.f};
  f32x4 acc[2][2];
#pragma unroll
  for (int m = 0; m < 2; ++m)
#pragma unroll
    for (int n = 0; n < 2; ++n) acc[m][n] = z4;

  for (int kt = 0; kt < 16; ++kt) {
    const int kbase = kt * 64;
#pragma unroll
    for (int issue = 0; issue < 2; ++issue) {
      int i = issue * 256 + tid;
      int r = i >> 3, jp = (i & 7) ^ (r & 7);
      gload16(A + (size_t)(m0 + r) * 1024 + kbase + jp * 8,
              lA + (size_t)(issue * 256 + (tid & ~63)) * 8);
      gload16(Bt + (size_t)(n0 + r) * 1024 + kbase + jp * 8,
              lB + (size_t)(issue * 256 + (tid & ~63)) * 8);
    }
    __syncthreads();
#pragma unroll
    for (int kk = 0; kk < 2; ++kk) {
      bf16x8 a[2], b[2];
#pragma unroll
      for (int m = 0; m < 2; ++m) {
        int row = wm * 32 + m * 16 + r16;
        int off = row * 128 + ((kk * 64 + g * 16) ^ ((r16 & 7) << 4));
        a[m] = *(const bf16x8*)((const char*)lA + off);
      }
#pragma unroll
      for (int n = 0; n < 2; ++n) {
        int row = wn * 32 + n * 16 + r16;
        int off = row * 128 + ((kk * 64 + g * 16) ^ ((r16 & 7) << 4));
        b[n] = *(const bf16x8*)((const char*)lB + off);
      }
      __builtin_amdgcn_s_setprio(1);
#pragma unroll
      for (int m = 0; m < 2; ++m)
#pragma unroll
        for (int n = 0; n < 2; ++n) acc[m][n] = mfma16(a[m], b[n], acc[m][n]);
      __builtin_amdgcn_s_setprio(0);
    }
    __syncthreads();
  }
#pragma unroll
  for (int m = 0; m < 2; ++m)
#pragma unroll
    for (int n = 0; n < 2; ++n) {
      int col = n0 + wn * 32 + n * 16 + r16;
#pragma unroll
      for (int j = 0; j < 4; ++j) {
        int row = m0 + wm * 32 + m * 16 + g * 4 + j;
        Cf[(size_t)row * N + col] = acc[m][n][j];
      }
    }
}

// ---------------- fused causal flash attention -------------------------------
// IN-REGISTER P: K-tile rows staged at sigma-permuted LDS positions
// (sigma(r): bits[b5,b3,b2,b4,b1,b0]) so the QK C-fragment's in-lane kv set
// {f*16+g*4+j} IS the PV A-fragment's required set {ks*32+g*8+c}. P = packed
// s[] regs, never touches LDS. lP deleted -> 32KB LDS/block.
// qk layout: [b*2048+n][2048] (Q cols 0..1023, K cols 1024..2047).

__global__ __launch_bounds__(256) void attn_fused(const u16* __restrict__ qk,
                                                  const u16* __restrict__ vt,
                                                  u16* __restrict__ ao) {
  __shared__ __align__(16) u16 lK[2][64 * 64];
  __shared__ __align__(16) u16 lV[2][64 * 64];
  const int tid = threadIdx.x;
  const int lane = tid & 63, w = tid >> 6;
  const int g = lane >> 4, r16 = lane & 15;

  const int flat = (int)blockIdx.x;
  const int xcd = flat & 7;
  const int cu = (flat >> 3) & 31;
  const int round = (flat >> 8) & 3;
  const int grp = xcd * 4 + round;               // b*16+h
  const int qt = (round & 1) ? cu : 31 - cu;     // per-CU resident set sums to 66
  const int b = grp >> 4, h = grp & 15;
  const int q0w = qt * 64 + w * 16;

  // Q fragments (q-row = r16), scale*log2e folded into wqkvT
  bf16x8 aq[2];
  {
    const u16* qrow = qk + (size_t)(b * 2048 + q0w + r16) * 2048 + h * 64;
    aq[0] = *(const bf16x8*)(qrow + g * 8);
    aq[1] = *(const bf16x8*)(qrow + 32 + g * 8);
  }

  const int r = tid >> 3, jp = (tid & 7) ^ (r & 7);  // LDS row r, chunk jp
  // sigma: LDS row r holds K row 32*(r>>5)+8*((r>>2)&3)+4*((r>>4)&1)+(r&3)
  const int rp = (r & 0x23) | ((r & 0x0C) << 1) | ((r & 0x10) >> 2);
  const u16* ksrc = qk + (size_t)(b * 2048 + rp) * 2048 + 1024 + h * 64 + jp * 8;
  const u16* vsrc = vt + (size_t)((b * 16 + h) * 64 + r) * 2048 + jp * 8;
  const size_t ldst = (size_t)(tid & ~63) * 8;

  const f32x4 z4 = {0.f, 0.f, 0.f, 0.f};
  f32x4 o[4];
#pragma unroll
  for (int n = 0; n < 4; ++n) o[n] = z4;
  float mrun = -INFINITY, lrun = 0.f;

  gload16(ksrc, lK[0] + ldst);
  gload16(ksrc + (size_t)32 * 2048, lK[0] + 2048 + ldst);   // sigma(r+32)=sigma(r)+32
  gload16(vsrc, lV[0] + ldst);
  gload16(vsrc + (size_t)32 * 2048, lV[0] + 2048 + ldst);
  __syncthreads();

  int cur = 0;
  for (int t = 0; t <= qt; ++t) {
    if (t < qt) {  // prefetch next K/V tile into the other buffer
      const u16* kn = ksrc + (size_t)(t + 1) * 64 * 2048;
      const u16* vn = vsrc + (size_t)(t + 1) * 64;
      gload16(kn, lK[cur ^ 1] + ldst);
      gload16(kn + (size_t)32 * 2048, lK[cur ^ 1] + 2048 + ldst);
      gload16(vn, lV[cur ^ 1] + ldst);
      gload16(vn + (size_t)32 * 2048, lV[cur ^ 1] + 2048 + ldst);
    }
    // S^T = K Q^T : s[f][j] -> q = r16, kv_true = 32*(f>>1)+8*g+4*(f&1)+j
    f32x4 s[4];
#pragma unroll
    for (int f = 0; f < 4; ++f) s[f] = z4;
    __builtin_amdgcn_s_setprio(1);
#pragma unroll
    for (int kk = 0; kk < 2; ++kk) {
#pragma unroll
      for (int f = 0; f < 4; ++f) {
        int row = f * 16 + r16;
        int off = row * 128 + ((kk * 64 + g * 16) ^ ((r16 & 7) << 4));
        bf16x8 ak = *(const bf16x8*)((const char*)lK[cur] + off);
        s[f] = mfma16(ak, aq[kk], s[f]);  // A = K rows (permuted), B = Q rows
      }
    }
    __builtin_amdgcn_s_setprio(0);
    if (t == qt) {  // diagonal tile: causal mask (kv_true > q)
      const int qrel = w * 16 + r16;
#pragma unroll
      for (int f = 0; f < 4; ++f)
#pragma unroll
        for (int j = 0; j < 4; ++j) {
          int kvt = (f >> 1) * 32 + g * 8 + (f & 1) * 4 + j;
          if (kvt > qrel) s[f][j] = -3.0e38f;
        }
    }
    // in-lane online softmax (exp2 domain), lane owns q-row r16
    float mx = fmaxf(fmaxf(fmaxf(s[0][0], s[0][1]), fmaxf(s[0][2], s[0][3])),
                     fmaxf(fmaxf(s[1][0], s[1][1]), fmaxf(s[1][2], s[1][3])));
    mx = fmaxf(mx, fmaxf(fmaxf(fmaxf(s[2][0], s[2][1]), fmaxf(s[2][2], s[2][3])),
                         fmaxf(fmaxf(s[3][0], s[3][1]), fmaxf(s[3][2], s[3][3]))));
    mx = fmaxf(mx, __shfl_xor(mx, 16));
    mx = fmaxf(mx, __shfl_xor(mx, 32));
    // defer-max (T13): skip the O-rescale unless some row grew past THR=8
    if (!__all(mx - mrun <= 8.0f)) {
      float mnew = fmaxf(mrun, mx);
      float corr = exp2fast(mrun - mnew);
      mrun = mnew;
      lrun *= corr;
      float cj[4];
#pragma unroll
      for (int j = 0; j < 4; ++j) cj[j] = __shfl(corr, g * 4 + j);
#pragma unroll
      for (int n = 0; n < 4; ++n)
#pragma unroll
        for (int j = 0; j < 4; ++j) o[n][j] *= cj[j];
    }
    float sm = 0.f;
#pragma unroll
    for (int f = 0; f < 4; ++f)
#pragma unroll
      for (int j = 0; j < 4; ++j) {
        s[f][j] = exp2fast(s[f][j] - mrun);
        sm += s[f][j];
      }
    sm += __shfl_xor(sm, 16);
    sm += __shfl_xor(sm, 32);
    lrun += sm;

    // pack P in-register: ks covers kv_true ks*32+g*8+{0..7} = s[2ks..2ks+1][*]
    u32 pa[8];
#pragma unroll
    for (int f = 0; f < 4; ++f) {
      pa[f * 2 + 0] = (u32)f2bf(s[f][0]) | ((u32)f2bf(s[f][1]) << 16);
      pa[f * 2 + 1] = (u32)f2bf(s[f][2]) | ((u32)f2bf(s[f][3]) << 16);
    }
    // PV: A = P (regs), B = V^T rows (d)
    __builtin_amdgcn_s_setprio(1);
#pragma unroll
    for (int ks = 0; ks < 2; ++ks) {
      u32x4 pav = { pa[ks * 4 + 0], pa[ks * 4 + 1], pa[ks * 4 + 2], pa[ks * 4 + 3] };
      bf16x8 ap = __builtin_bit_cast(bf16x8, pav);
#pragma unroll
      for (int n = 0; n < 4; ++n) {
        int row = n * 16 + r16;
        int off = row * 128 + ((ks * 64 + g * 16) ^ ((r16 & 7) << 4));
        bf16x8 bv = *(const bf16x8*)((const char*)lV[cur] + off);
        o[n] = mfma16(ap, bv, o[n]);
      }
    }
    __builtin_amdgcn_s_setprio(0);
    __syncthreads();  // drains prefetch + protects buffer swap
    cur ^= 1;
  }
  // epilogue: O rows = q = g*4+j, cols = d = n*16+r16
  float lj[4];
#pragma unroll
  for (int j = 0; j < 4; ++j) lj[j] = __shfl(lrun, g * 4 + j);
#pragma unroll
  for (int n = 0; n < 4; ++n) {
    int col = h * 64 + n * 16 + r16;
#pragma unroll
    for (int j = 0; j < 4; ++j) {
      int row = b * 2048 + q0w + g * 4 + j;
      ao[(size_t)row * 1024 + col] = f2bf(o[n][j] * (1.f / lj[j]));
    }
  }
}

// ---------------- launch ----------------

extern "C" void kernel_launch(void* const* d_in, const int* in_sizes, int n_in,
                              void* d_out, int out_size, void* d_ws, size_t ws_size,
                              hipStream_t stream) {
  const float* x     = (const float*)d_in[0];
  // d_in[1] = attn_mask: causal tril, implemented analytically — unused.
  const float* w_qkv = (const float*)d_in[2];
  const float* w_out = (const float*)d_in[3];
  float* out = (float*)d_out;

  u16* ws = (u16*)d_ws;
  u16* x_bf  = ws;                               // 4096*1024  (4M)
  u16* wqkvT = x_bf + (size_t)4096 * 1024;       // 3072*1024  (3M)
  u16* woutT = wqkvT + (size_t)3072 * 1024;      // 1024*1024  (1M)
  u16* qk    = woutT + (size_t)1024 * 1024;      // 4096*2048  (8M)
  u16* vtb   = qk + (size_t)4096 * 2048;         // 2048*2048  (4M)
  u16* ao    = vtb + (size_t)2048 * 2048;        // 4096*1024  (4M)  -> 24M u16 total

  cvt_x<<<4096, 256, 0, stream>>>(x, x_bf);
  wtrans_all<<<dim3(64, 16), 256, 0, stream>>>(w_qkv, w_out, wqkvT, woutT);
  gemm_bf16<<<768, 256, 0, stream>>>(x_bf, wqkvT, qk, vtb, 24, 96);
  attn_fused<<<1024, 256, 0, stream>>>(qk, vtb, ao);
  gemm64<<<1024, 256, 0, stream>>>(ao, woutT, out, 1024, 16, 128);
}

// Round 9
// 194.696 us; speedup vs baseline: 1.0205x; 1.0205x over previous
//
#include <hip/hip_runtime.h>
#include <hip/hip_bf16.h>

// B=2, N=2048, D=1024, H=16, DH=64. f32 in / f32 out, bf16 MFMA internally.

typedef unsigned short u16;
typedef unsigned int u32;
typedef __bf16 bf16x8 __attribute__((ext_vector_type(8)));
typedef float  f32x4  __attribute__((ext_vector_type(4)));
typedef unsigned short u16x4 __attribute__((ext_vector_type(4)));

#define DEV __device__ __forceinline__

DEV float exp2fast(float x) { return __builtin_amdgcn_exp2f(x); }  // v_exp_f32

DEV u16 f2bf(float f) {  // RNE, used in prep/gemm epilogues
  unsigned u = __builtin_bit_cast(unsigned, f);
  return (u16)((u + 0x7FFFu + ((u >> 16) & 1u)) >> 16);
}

DEV u16 f2bf_fast(float f) {  // native cast -> v_cvt (attn hot path)
  __bf16 h = (__bf16)f;
  return __builtin_bit_cast(u16, h);
}

DEV f32x4 mfma16(bf16x8 a, bf16x8 b, f32x4 c) {
  return __builtin_amdgcn_mfma_f32_16x16x32_bf16(a, b, c, 0, 0, 0);
}

template <typename T>
DEV void gload16(const T* g, T* l) {  // global -> LDS, 16B per lane, dest = base + lane*16
  __builtin_amdgcn_global_load_lds((__attribute__((address_space(1))) void*)g,
                                   (__attribute__((address_space(3))) void*)l, 16, 0, 0);
}

// ---------------- prep kernels ----------------

__global__ __launch_bounds__(256) void cvt_x(const float* __restrict__ x,
                                             u16* __restrict__ xb) {
  int idx = (blockIdx.x * 256 + threadIdx.x) * 4;
  float4 v = *(const float4*)(x + idx);
  u16x4 u = { f2bf(v.x), f2bf(v.y), f2bf(v.z), f2bf(v.w) };
  *(u16x4*)(xb + idx) = u;
}

// merged weight transpose: bx<48 -> w_qkv (C=3072, q-scale on cols<1024),
// else w_out (C=1024). dst[c][r] = bf16(src[r][c] * scale), R=1024.
__global__ __launch_bounds__(256) void wtrans_all(const float* __restrict__ wq,
                                                  const float* __restrict__ wo,
                                                  u16* __restrict__ dq,
                                                  u16* __restrict__ dow) {
  __shared__ u16 T[64][72];
  const int tid = threadIdx.x;
  int bx = blockIdx.x;
  const float* src; u16* dst; int C, sl;
  if (bx < 48) { src = wq; dst = dq; C = 3072; sl = 1024; }
  else         { bx -= 48; src = wo; dst = dow; C = 1024; sl = 0; }
  const int c0 = bx * 64, r0 = blockIdx.y * 64;
  const int cl = tid & 63;
  // q-scale folded: 1/sqrt(64) * log2(e)  (softmax runs in exp2 domain)
  const float scale = (c0 + cl < sl) ? 0.125f * 1.4426950408889634f : 1.0f;
#pragma unroll
  for (int i = 0; i < 16; ++i) {
    int r = (tid >> 6) * 16 + i;
    T[cl][r] = f2bf(src[(size_t)(r0 + r) * C + c0 + cl] * scale);
  }
  __syncthreads();
#pragma unroll
  for (int i = 0; i < 16; ++i) {
    int cc = (tid >> 6) * 16 + i;
    dst[(size_t)(c0 + cc) * 1024 + r0 + cl] = T[cc][cl];
  }
}

// ---------------- GEMM1: [4096,1024] x [3072,1024]^T, 128x128 tile ----------
// Q/K cols (n0<2048) -> qk[row][2048]; V cols -> vt[b][h][d][n] directly.

__global__ __launch_bounds__(256) void gemm_bf16(const u16* __restrict__ A,
                                                 const u16* __restrict__ Bt,
                                                 u16* __restrict__ qk,
                                                 u16* __restrict__ vt,
                                                 int nx, int cpx) {
  __shared__ __align__(16) u16 lA[128 * 64];
  __shared__ __align__(16) u16 lB[128 * 64];
  const int tid = threadIdx.x;
  const int lane = tid & 63, w = tid >> 6;
  const int g = lane >> 4, r16 = lane & 15;
  const int wm = w >> 1, wn = w & 1;
  const int id = (int)blockIdx.x;
  const int newid = (id & 7) * cpx + (id >> 3);  // nwg % 8 == 0
  const int m0 = (newid / nx) * 128, n0 = (newid % nx) * 128;

  const f32x4 z4 = {0.f, 0.f, 0.f, 0.f};
  f32x4 acc[4][4];
#pragma unroll
  for (int m = 0; m < 4; ++m)
#pragma unroll
    for (int n = 0; n < 4; ++n) acc[m][n] = z4;

  for (int kt = 0; kt < 16; ++kt) {
    const int kbase = kt * 64;
#pragma unroll
    for (int issue = 0; issue < 4; ++issue) {
      int i = issue * 256 + tid;
      int r = i >> 3, jp = (i & 7) ^ (r & 7);  // swizzled source chunk
      gload16(A + (size_t)(m0 + r) * 1024 + kbase + jp * 8,
              lA + (size_t)(issue * 256 + (tid & ~63)) * 8);
      gload16(Bt + (size_t)(n0 + r) * 1024 + kbase + jp * 8,
              lB + (size_t)(issue * 256 + (tid & ~63)) * 8);
    }
    __syncthreads();
#pragma unroll
    for (int kk = 0; kk < 2; ++kk) {
      bf16x8 a[4], b[4];
#pragma unroll
      for (int m = 0; m < 4; ++m) {
        int row = wm * 64 + m * 16 + r16;
        int off = row * 128 + ((kk * 64 + g * 16) ^ ((r16 & 7) << 4));
        a[m] = *(const bf16x8*)((const char*)lA + off);
      }
#pragma unroll
      for (int n = 0; n < 4; ++n) {
        int row = wn * 64 + n * 16 + r16;
        int off = row * 128 + ((kk * 64 + g * 16) ^ ((r16 & 7) << 4));
        b[n] = *(const bf16x8*)((const char*)lB + off);
      }
      __builtin_amdgcn_s_setprio(1);
#pragma unroll
      for (int m = 0; m < 4; ++m)
#pragma unroll
        for (int n = 0; n < 4; ++n) acc[m][n] = mfma16(a[m], b[n], acc[m][n]);
      __builtin_amdgcn_s_setprio(0);
    }
    __syncthreads();
  }
  if (n0 < 2048) {  // Q/K -> qk[row][2048]
#pragma unroll
    for (int m = 0; m < 4; ++m)
#pragma unroll
      for (int n = 0; n < 4; ++n) {
        int col = n0 + wn * 64 + n * 16 + r16;
#pragma unroll
        for (int j = 0; j < 4; ++j) {
          int row = m0 + wm * 64 + m * 16 + g * 4 + j;
          qk[(size_t)row * 2048 + col] = f2bf(acc[m][n][j]);
        }
      }
  } else {  // V -> vt[(b*16+h)*64+d][2048] packed 4-row u16x4 stores
#pragma unroll
    for (int m = 0; m < 4; ++m) {
      int row0 = m0 + wm * 64 + m * 16 + g * 4;  // j = 0..3 consecutive rows
      int b = row0 >> 11, nn0 = row0 & 2047;
#pragma unroll
      for (int n = 0; n < 4; ++n) {
        int hcol = n0 - 2048 + wn * 64 + n * 16 + r16;
        int h = hcol >> 6, d = hcol & 63;
        u16x4 pk = { f2bf(acc[m][n][0]), f2bf(acc[m][n][1]),
                     f2bf(acc[m][n][2]), f2bf(acc[m][n][3]) };
        *(u16x4*)(vt + (size_t)((b * 16 + h) * 64 + d) * 2048 + nn0) = pk;
      }
    }
  }
}

// ---------------- GEMM2: 64x64 tile (4 blocks/CU) --------------------------

__global__ __launch_bounds__(256) void gemm64(const u16* __restrict__ A,
                                              const u16* __restrict__ Bt,
                                              float* __restrict__ Cf,
                                              int N, int nx, int cpx) {
  __shared__ __align__(16) u16 lA[64 * 64];
  __shared__ __align__(16) u16 lB[64 * 64];
  const int tid = threadIdx.x;
  const int lane = tid & 63, w = tid >> 6;
  const int g = lane >> 4, r16 = lane & 15;
  const int wm = w >> 1, wn = w & 1;
  const int id = (int)blockIdx.x;
  const int newid = (id & 7) * cpx + (id >> 3);
  const int m0 = (newid / nx) * 64, n0 = (newid % nx) * 64;

  const f32x4 z4 = {0.f, 0.f, 0.f, 0.f};
  f32x4 acc[2][2];
#pragma unroll
  for (int m = 0; m < 2; ++m)
#pragma unroll
    for (int n = 0; n < 2; ++n) acc[m][n] = z4;

  for (int kt = 0; kt < 16; ++kt) {
    const int kbase = kt * 64;
#pragma unroll
    for (int issue = 0; issue < 2; ++issue) {
      int i = issue * 256 + tid;
      int r = i >> 3, jp = (i & 7) ^ (r & 7);
      gload16(A + (size_t)(m0 + r) * 1024 + kbase + jp * 8,
              lA + (size_t)(issue * 256 + (tid & ~63)) * 8);
      gload16(Bt + (size_t)(n0 + r) * 1024 + kbase + jp * 8,
              lB + (size_t)(issue * 256 + (tid & ~63)) * 8);
    }
    __syncthreads();
#pragma unroll
    for (int kk = 0; kk < 2; ++kk) {
      bf16x8 a[2], b[2];
#pragma unroll
      for (int m = 0; m < 2; ++m) {
        int row = wm * 32 + m * 16 + r16;
        int off = row * 128 + ((kk * 64 + g * 16) ^ ((r16 & 7) << 4));
        a[m] = *(const bf16x8*)((const char*)lA + off);
      }
#pragma unroll
      for (int n = 0; n < 2; ++n) {
        int row = wn * 32 + n * 16 + r16;
        int off = row * 128 + ((kk * 64 + g * 16) ^ ((r16 & 7) << 4));
        b[n] = *(const bf16x8*)((const char*)lB + off);
      }
      __builtin_amdgcn_s_setprio(1);
#pragma unroll
      for (int m = 0; m < 2; ++m)
#pragma unroll
        for (int n = 0; n < 2; ++n) acc[m][n] = mfma16(a[m], b[n], acc[m][n]);
      __builtin_amdgcn_s_setprio(0);
    }
    __syncthreads();
  }
#pragma unroll
  for (int m = 0; m < 2; ++m)
#pragma unroll
    for (int n = 0; n < 2; ++n) {
      int col = n0 + wn * 32 + n * 16 + r16;
#pragma unroll
      for (int j = 0; j < 4; ++j) {
        int row = m0 + wm * 32 + m * 16 + g * 4 + j;
        Cf[(size_t)row * N + col] = acc[m][n][j];
      }
    }
}

// ---------------- fused causal flash attention -------------------------------
// In-register P (sigma-permuted K staging, R8). This round:
// (1) per-CU CONCURRENCY balance: rounds give qts {31-cu, cu, (47-cu)&31,
//     (16+cu)&31} -> per-CU step sets {~32,~1,~16,~17}: one long block always
//     overlapped by two medium ones (was {32,1,32,1}: 2-way on critical CUs).
// (2) native bf16 casts for P packing (compiler v_cvt; manual RNE was 4-5 ops).
// (3) deferred l-reduction: lrun per-lane partial, row-reduce once in epilogue
//     (corr is row-uniform so partial scaling commutes). Saves 2 shfl/step.

__global__ __launch_bounds__(256) void attn_fused(const u16* __restrict__ qk,
                                                  const u16* __restrict__ vt,
                                                  u16* __restrict__ ao) {
  __shared__ __align__(16) u16 lK[2][64 * 64];
  __shared__ __align__(16) u16 lV[2][64 * 64];
  const int tid = threadIdx.x;
  const int lane = tid & 63, w = tid >> 6;
  const int g = lane >> 4, r16 = lane & 15;

  const int flat = (int)blockIdx.x;
  const int xcd = flat & 7;
  const int cu = (flat >> 3) & 31;
  const int round = (flat >> 8) & 3;
  const int grp = xcd * 4 + round;               // b*16+h
  int qt;
  if (round == 0)      qt = 31 - cu;
  else if (round == 1) qt = cu;
  else if (round == 2) qt = (47 - cu) & 31;
  else                 qt = (16 + cu) & 31;
  const int b = grp >> 4, h = grp & 15;
  const int q0w = qt * 64 + w * 16;

  // Q fragments (q-row = r16), scale*log2e folded into wqkvT
  bf16x8 aq[2];
  {
    const u16* qrow = qk + (size_t)(b * 2048 + q0w + r16) * 2048 + h * 64;
    aq[0] = *(const bf16x8*)(qrow + g * 8);
    aq[1] = *(const bf16x8*)(qrow + 32 + g * 8);
  }

  const int r = tid >> 3, jp = (tid & 7) ^ (r & 7);  // LDS row r, chunk jp
  // sigma: LDS row r holds K row 32*(r>>5)+8*((r>>2)&3)+4*((r>>4)&1)+(r&3)
  const int rp = (r & 0x23) | ((r & 0x0C) << 1) | ((r & 0x10) >> 2);
  const u16* ksrc = qk + (size_t)(b * 2048 + rp) * 2048 + 1024 + h * 64 + jp * 8;
  const u16* vsrc = vt + (size_t)((b * 16 + h) * 64 + r) * 2048 + jp * 8;
  const size_t ldst = (size_t)(tid & ~63) * 8;

  const f32x4 z4 = {0.f, 0.f, 0.f, 0.f};
  f32x4 o[4];
#pragma unroll
  for (int n = 0; n < 4; ++n) o[n] = z4;
  float mrun = -INFINITY, lrun = 0.f;  // lrun = per-lane PARTIAL (16 kv slots)

  gload16(ksrc, lK[0] + ldst);
  gload16(ksrc + (size_t)32 * 2048, lK[0] + 2048 + ldst);   // sigma(r+32)=sigma(r)+32
  gload16(vsrc, lV[0] + ldst);
  gload16(vsrc + (size_t)32 * 2048, lV[0] + 2048 + ldst);
  __syncthreads();

  int cur = 0;
  for (int t = 0; t <= qt; ++t) {
    if (t < qt) {  // prefetch next K/V tile into the other buffer
      const u16* kn = ksrc + (size_t)(t + 1) * 64 * 2048;
      const u16* vn = vsrc + (size_t)(t + 1) * 64;
      gload16(kn, lK[cur ^ 1] + ldst);
      gload16(kn + (size_t)32 * 2048, lK[cur ^ 1] + 2048 + ldst);
      gload16(vn, lV[cur ^ 1] + ldst);
      gload16(vn + (size_t)32 * 2048, lV[cur ^ 1] + 2048 + ldst);
    }
    // S^T = K Q^T : s[f][j] -> q = r16, kv_true = 32*(f>>1)+8*g+4*(f&1)+j
    f32x4 s[4];
#pragma unroll
    for (int f = 0; f < 4; ++f) s[f] = z4;
    __builtin_amdgcn_s_setprio(1);
#pragma unroll
    for (int kk = 0; kk < 2; ++kk) {
#pragma unroll
      for (int f = 0; f < 4; ++f) {
        int row = f * 16 + r16;
        int off = row * 128 + ((kk * 64 + g * 16) ^ ((r16 & 7) << 4));
        bf16x8 ak = *(const bf16x8*)((const char*)lK[cur] + off);
        s[f] = mfma16(ak, aq[kk], s[f]);  // A = K rows (permuted), B = Q rows
      }
    }
    __builtin_amdgcn_s_setprio(0);
    if (t == qt) {  // diagonal tile: causal mask (kv_true > q)
      const int qrel = w * 16 + r16;
#pragma unroll
      for (int f = 0; f < 4; ++f)
#pragma unroll
        for (int j = 0; j < 4; ++j) {
          int kvt = (f >> 1) * 32 + g * 8 + (f & 1) * 4 + j;
          if (kvt > qrel) s[f][j] = -3.0e38f;
        }
    }
    // in-lane online softmax (exp2 domain), lane owns q-row r16
    float mx = fmaxf(fmaxf(fmaxf(s[0][0], s[0][1]), fmaxf(s[0][2], s[0][3])),
                     fmaxf(fmaxf(s[1][0], s[1][1]), fmaxf(s[1][2], s[1][3])));
    mx = fmaxf(mx, fmaxf(fmaxf(fmaxf(s[2][0], s[2][1]), fmaxf(s[2][2], s[2][3])),
                         fmaxf(fmaxf(s[3][0], s[3][1]), fmaxf(s[3][2], s[3][3]))));
    mx = fmaxf(mx, __shfl_xor(mx, 16));
    mx = fmaxf(mx, __shfl_xor(mx, 32));
    // defer-max (T13): skip the O-rescale unless some row grew past THR=8
    if (!__all(mx - mrun <= 8.0f)) {
      float mnew = fmaxf(mrun, mx);
      float corr = exp2fast(mrun - mnew);
      mrun = mnew;
      lrun *= corr;  // row-uniform corr: partial scaling commutes
      float cj[4];
#pragma unroll
      for (int j = 0; j < 4; ++j) cj[j] = __shfl(corr, g * 4 + j);
#pragma unroll
      for (int n = 0; n < 4; ++n)
#pragma unroll
        for (int j = 0; j < 4; ++j) o[n][j] *= cj[j];
    }
    float sm = 0.f;
#pragma unroll
    for (int f = 0; f < 4; ++f)
#pragma unroll
      for (int j = 0; j < 4; ++j) {
        s[f][j] = exp2fast(s[f][j] - mrun);
        sm += s[f][j];
      }
    lrun += sm;  // per-lane partial; row-reduced once in epilogue

    // pack P in-register with native casts (v_cvt): ap[ks] covers
    // kv_true ks*32+g*8+{0..7} = s[2ks][0..3], s[2ks+1][0..3]
    bf16x8 ap0, ap1;
#pragma unroll
    for (int j = 0; j < 4; ++j) {
      ap0[j]     = (__bf16)s[0][j];
      ap0[j + 4] = (__bf16)s[1][j];
      ap1[j]     = (__bf16)s[2][j];
      ap1[j + 4] = (__bf16)s[3][j];
    }
    // PV: A = P (regs), B = V^T rows (d)
    __builtin_amdgcn_s_setprio(1);
#pragma unroll
    for (int n = 0; n < 4; ++n) {
      int row = n * 16 + r16;
      int off0 = row * 128 + ((g * 16) ^ ((r16 & 7) << 4));
      int off1 = row * 128 + ((64 + g * 16) ^ ((r16 & 7) << 4));
      bf16x8 bv0 = *(const bf16x8*)((const char*)lV[cur] + off0);
      o[n] = mfma16(ap0, bv0, o[n]);
      bf16x8 bv1 = *(const bf16x8*)((const char*)lV[cur] + off1);
      o[n] = mfma16(ap1, bv1, o[n]);
    }
    __builtin_amdgcn_s_setprio(0);
    __syncthreads();  // drains prefetch + protects buffer swap
    cur ^= 1;
  }
  // epilogue: row-reduce lrun, then O rows = q = g*4+j, cols = d = n*16+r16
  float lt = lrun;
  lt += __shfl_xor(lt, 16);
  lt += __shfl_xor(lt, 32);
  float lj[4];
#pragma unroll
  for (int j = 0; j < 4; ++j) lj[j] = __shfl(lt, g * 4 + j);
#pragma unroll
  for (int n = 0; n < 4; ++n) {
    int col = h * 64 + n * 16 + r16;
#pragma unroll
    for (int j = 0; j < 4; ++j) {
      int row = b * 2048 + q0w + g * 4 + j;
      ao[(size_t)row * 1024 + col] = f2bf_fast(o[n][j] * (1.f / lj[j]));
    }
  }
}

// ---------------- launch ----------------

extern "C" void kernel_launch(void* const* d_in, const int* in_sizes, int n_in,
                              void* d_out, int out_size, void* d_ws, size_t ws_size,
                              hipStream_t stream) {
  const float* x     = (const float*)d_in[0];
  // d_in[1] = attn_mask: causal tril, implemented analytically — unused.
  const float* w_qkv = (const float*)d_in[2];
  const float* w_out = (const float*)d_in[3];
  float* out = (float*)d_out;

  u16* ws = (u16*)d_ws;
  u16* x_bf  = ws;                               // 4096*1024  (4M)
  u16* wqkvT = x_bf + (size_t)4096 * 1024;       // 3072*1024  (3M)
  u16* woutT = wqkvT + (size_t)3072 * 1024;      // 1024*1024  (1M)
  u16* qk    = woutT + (size_t)1024 * 1024;      // 4096*2048  (8M)
  u16* vtb   = qk + (size_t)4096 * 2048;         // 2048*2048  (4M)
  u16* ao    = vtb + (size_t)2048 * 2048;        // 4096*1024  (4M)

  cvt_x<<<4096, 256, 0, stream>>>(x, x_bf);
  wtrans_all<<<dim3(64, 16), 256, 0, stream>>>(w_qkv, w_out, wqkvT, woutT);
  gemm_bf16<<<768, 256, 0, stream>>>(x_bf, wqkvT, qk, vtb, 24, 96);
  attn_fused<<<1024, 256, 0, stream>>>(qk, vtb, ao);
  gemm64<<<1024, 256, 0, stream>>>(ao, woutT, out, 1024, 16, 128);
}

// Round 11
// 192.764 us; speedup vs baseline: 1.0307x; 1.0100x over previous
//
#include <hip/hip_runtime.h>
#include <hip/hip_bf16.h>

// B=2, N=2048, D=1024, H=16, DH=64. f32 in / f32 out, bf16 MFMA internally.

typedef unsigned short u16;
typedef unsigned int u32;
typedef __bf16 bf16x8 __attribute__((ext_vector_type(8)));
typedef float  f32x4  __attribute__((ext_vector_type(4)));
typedef unsigned short u16x4 __attribute__((ext_vector_type(4)));

#define DEV __device__ __forceinline__

DEV float exp2fast(float x) { return __builtin_amdgcn_exp2f(x); }  // v_exp_f32

DEV u16 f2bf(float f) {  // RNE, used in prep/gemm epilogues
  unsigned u = __builtin_bit_cast(unsigned, f);
  return (u16)((u + 0x7FFFu + ((u >> 16) & 1u)) >> 16);
}

DEV u16 f2bf_fast(float f) {  // native cast -> v_cvt (attn hot path)
  __bf16 h = (__bf16)f;
  return __builtin_bit_cast(u16, h);
}

DEV f32x4 mfma16(bf16x8 a, bf16x8 b, f32x4 c) {
  return __builtin_amdgcn_mfma_f32_16x16x32_bf16(a, b, c, 0, 0, 0);
}

template <typename T>
DEV void gload16(const T* g, T* l) {  // global -> LDS, 16B per lane, dest = base + lane*16
  __builtin_amdgcn_global_load_lds((__attribute__((address_space(1))) void*)g,
                                   (__attribute__((address_space(3))) void*)l, 16, 0, 0);
}

// ---------------- merged prep: x-convert + both weight transposes ----------
// id < 4096: cvt_x tile; else weight-transpose tile (wid<768 -> w_qkv, else w_out)

__global__ __launch_bounds__(256) void prep(const float* __restrict__ x,
                                            const float* __restrict__ wq,
                                            const float* __restrict__ wo,
                                            u16* __restrict__ xb,
                                            u16* __restrict__ dq,
                                            u16* __restrict__ dow) {
  __shared__ u16 T[64][72];
  const int tid = threadIdx.x;
  const int id = (int)blockIdx.x;
  if (id < 4096) {  // x f32 -> bf16, 1024 elems/block
    int idx = (id * 256 + tid) * 4;
    float4 v = *(const float4*)(x + idx);
    u16x4 u = { f2bf(v.x), f2bf(v.y), f2bf(v.z), f2bf(v.w) };
    *(u16x4*)(xb + idx) = u;
    return;
  }
  int wid = id - 4096;                  // [0, 1024)
  int bx = wid & 63, by = wid >> 6;     // 64 x 16 tiles
  const float* src; u16* dst; int C, sl;
  if (bx < 48) { src = wq; dst = dq; C = 3072; sl = 1024; }
  else         { bx -= 48; src = wo; dst = dow; C = 1024; sl = 0; }
  const int c0 = bx * 64, r0 = by * 64;
  const int cl = tid & 63;
  // q-scale folded: 1/sqrt(64) * log2(e)  (softmax runs in exp2 domain)
  const float scale = (c0 + cl < sl) ? 0.125f * 1.4426950408889634f : 1.0f;
#pragma unroll
  for (int i = 0; i < 16; ++i) {
    int r = (tid >> 6) * 16 + i;
    T[cl][r] = f2bf(src[(size_t)(r0 + r) * C + c0 + cl] * scale);
  }
  __syncthreads();
#pragma unroll
  for (int i = 0; i < 16; ++i) {
    int cc = (tid >> 6) * 16 + i;
    dst[(size_t)(c0 + cc) * 1024 + r0 + cl] = T[cc][cl];
  }
}

// ---------------- GEMM1: [4096,1024] x [3072,1024]^T, 128x128 tile ----------
// Q/K cols (n0<2048) -> qk[row][2048]; V cols -> vt[b][h][d][n] directly.

__global__ __launch_bounds__(256) void gemm_bf16(const u16* __restrict__ A,
                                                 const u16* __restrict__ Bt,
                                                 u16* __restrict__ qk,
                                                 u16* __restrict__ vt,
                                                 int nx, int cpx) {
  __shared__ __align__(16) u16 lA[128 * 64];
  __shared__ __align__(16) u16 lB[128 * 64];
  const int tid = threadIdx.x;
  const int lane = tid & 63, w = tid >> 6;
  const int g = lane >> 4, r16 = lane & 15;
  const int wm = w >> 1, wn = w & 1;
  const int id = (int)blockIdx.x;
  const int newid = (id & 7) * cpx + (id >> 3);  // nwg % 8 == 0
  const int m0 = (newid / nx) * 128, n0 = (newid % nx) * 128;

  const f32x4 z4 = {0.f, 0.f, 0.f, 0.f};
  f32x4 acc[4][4];
#pragma unroll
  for (int m = 0; m < 4; ++m)
#pragma unroll
    for (int n = 0; n < 4; ++n) acc[m][n] = z4;

  for (int kt = 0; kt < 16; ++kt) {
    const int kbase = kt * 64;
#pragma unroll
    for (int issue = 0; issue < 4; ++issue) {
      int i = issue * 256 + tid;
      int r = i >> 3, jp = (i & 7) ^ (r & 7);  // swizzled source chunk
      gload16(A + (size_t)(m0 + r) * 1024 + kbase + jp * 8,
              lA + (size_t)(issue * 256 + (tid & ~63)) * 8);
      gload16(Bt + (size_t)(n0 + r) * 1024 + kbase + jp * 8,
              lB + (size_t)(issue * 256 + (tid & ~63)) * 8);
    }
    __syncthreads();
#pragma unroll
    for (int kk = 0; kk < 2; ++kk) {
      bf16x8 a[4], b[4];
#pragma unroll
      for (int m = 0; m < 4; ++m) {
        int row = wm * 64 + m * 16 + r16;
        int off = row * 128 + ((kk * 64 + g * 16) ^ ((r16 & 7) << 4));
        a[m] = *(const bf16x8*)((const char*)lA + off);
      }
#pragma unroll
      for (int n = 0; n < 4; ++n) {
        int row = wn * 64 + n * 16 + r16;
        int off = row * 128 + ((kk * 64 + g * 16) ^ ((r16 & 7) << 4));
        b[n] = *(const bf16x8*)((const char*)lB + off);
      }
      __builtin_amdgcn_s_setprio(1);
#pragma unroll
      for (int m = 0; m < 4; ++m)
#pragma unroll
        for (int n = 0; n < 4; ++n) acc[m][n] = mfma16(a[m], b[n], acc[m][n]);
      __builtin_amdgcn_s_setprio(0);
    }
    __syncthreads();
  }
  if (n0 < 2048) {  // Q/K -> qk[row][2048]
#pragma unroll
    for (int m = 0; m < 4; ++m)
#pragma unroll
      for (int n = 0; n < 4; ++n) {
        int col = n0 + wn * 64 + n * 16 + r16;
#pragma unroll
        for (int j = 0; j < 4; ++j) {
          int row = m0 + wm * 64 + m * 16 + g * 4 + j;
          qk[(size_t)row * 2048 + col] = f2bf(acc[m][n][j]);
        }
      }
  } else {  // V -> vt[(b*16+h)*64+d][2048] packed 4-row u16x4 stores
#pragma unroll
    for (int m = 0; m < 4; ++m) {
      int row0 = m0 + wm * 64 + m * 16 + g * 4;  // j = 0..3 consecutive rows
      int b = row0 >> 11, nn0 = row0 & 2047;
#pragma unroll
      for (int n = 0; n < 4; ++n) {
        int hcol = n0 - 2048 + wn * 64 + n * 16 + r16;
        int h = hcol >> 6, d = hcol & 63;
        u16x4 pk = { f2bf(acc[m][n][0]), f2bf(acc[m][n][1]),
                     f2bf(acc[m][n][2]), f2bf(acc[m][n][3]) };
        *(u16x4*)(vt + (size_t)((b * 16 + h) * 64 + d) * 2048 + nn0) = pk;
      }
    }
  }
}

// ---------------- GEMM2: 64x64 tile (4 blocks/CU) --------------------------

__global__ __launch_bounds__(256) void gemm64(const u16* __restrict__ A,
                                              const u16* __restrict__ Bt,
                                              float* __restrict__ Cf,
                                              int N, int nx, int cpx) {
  __shared__ __align__(16) u16 lA[64 * 64];
  __shared__ __align__(16) u16 lB[64 * 64];
  const int tid = threadIdx.x;
  const int lane = tid & 63, w = tid >> 6;
  const int g = lane >> 4, r16 = lane & 15;
  const int wm = w >> 1, wn = w & 1;
  const int id = (int)blockIdx.x;
  const int newid = (id & 7) * cpx + (id >> 3);
  const int m0 = (newid / nx) * 64, n0 = (newid % nx) * 64;

  const f32x4 z4 = {0.f, 0.f, 0.f, 0.f};
  f32x4 acc[2][2];
#pragma unroll
  for (int m = 0; m < 2; ++m)
#pragma unroll
    for (int n = 0; n < 2; ++n) acc[m][n] = z4;

  for (int kt = 0; kt < 16; ++kt) {
    const int kbase = kt * 64;
#pragma unroll
    for (int issue = 0; issue < 2; ++issue) {
      int i = issue * 256 + tid;
      int r = i >> 3, jp = (i & 7) ^ (r & 7);
      gload16(A + (size_t)(m0 + r) * 1024 + kbase + jp * 8,
              lA + (size_t)(issue * 256 + (tid & ~63)) * 8);
      gload16(Bt + (size_t)(n0 + r) * 1024 + kbase + jp * 8,
              lB + (size_t)(issue * 256 + (tid & ~63)) * 8);
    }
    __syncthreads();
#pragma unroll
    for (int kk = 0; kk < 2; ++kk) {
      bf16x8 a[2], b[2];
#pragma unroll
      for (int m = 0; m < 2; ++m) {
        int row = wm * 32 + m * 16 + r16;
        int off = row * 128 + ((kk * 64 + g * 16) ^ ((r16 & 7) << 4));
        a[m] = *(const bf16x8*)((const char*)lA + off);
      }
#pragma unroll
      for (int n = 0; n < 2; ++n) {
        int row = wn * 32 + n * 16 + r16;
        int off = row * 128 + ((kk * 64 + g * 16) ^ ((r16 & 7) << 4));
        b[n] = *(const bf16x8*)((const char*)lB + off);
      }
      __builtin_amdgcn_s_setprio(1);
#pragma unroll
      for (int m = 0; m < 2; ++m)
#pragma unroll
        for (int n = 0; n < 2; ++n) acc[m][n] = mfma16(a[m], b[n], acc[m][n]);
      __builtin_amdgcn_s_setprio(0);
    }
    __syncthreads();
  }
#pragma unroll
  for (int m = 0; m < 2; ++m)
#pragma unroll
    for (int n = 0; n < 2; ++n) {
      int col = n0 + wn * 32 + n * 16 + r16;
#pragma unroll
      for (int j = 0; j < 4; ++j) {
        int row = m0 + wm * 32 + m * 16 + g * 4 + j;
        Cf[(size_t)row * N + col] = acc[m][n][j];
      }
    }
}

// ---------------- fused causal flash attention -------------------------------
// In-register P (sigma-permuted K staging). Concurrency-balanced decode:
// rounds {0,1} -> qt = 31-cu, rounds {2,3} -> qt = cu  =>  every CU holds
// {32-cu, 32-cu, cu+1, cu+1} steps: the two equal-length long blocks cover
// each other to completion (2-way min concurrency; was {32,17,16,1} with a
// 15-step lone-wolf tail on the critical CU).

__global__ __launch_bounds__(256) void attn_fused(const u16* __restrict__ qk,
                                                  const u16* __restrict__ vt,
                                                  u16* __restrict__ ao) {
  __shared__ __align__(16) u16 lK[2][64 * 64];
  __shared__ __align__(16) u16 lV[2][64 * 64];
  const int tid = threadIdx.x;
  const int lane = tid & 63, w = tid >> 6;
  const int g = lane >> 4, r16 = lane & 15;

  const int flat = (int)blockIdx.x;
  const int xcd = flat & 7;
  const int cu = (flat >> 3) & 31;
  const int round = (flat >> 8) & 3;
  const int grp = xcd * 4 + round;               // b*16+h
  const int qt = (round < 2) ? (31 - cu) : cu;
  const int b = grp >> 4, h = grp & 15;
  const int q0w = qt * 64 + w * 16;

  // Q fragments (q-row = r16), scale*log2e folded into wqkvT
  bf16x8 aq[2];
  {
    const u16* qrow = qk + (size_t)(b * 2048 + q0w + r16) * 2048 + h * 64;
    aq[0] = *(const bf16x8*)(qrow + g * 8);
    aq[1] = *(const bf16x8*)(qrow + 32 + g * 8);
  }

  const int r = tid >> 3, jp = (tid & 7) ^ (r & 7);  // LDS row r, chunk jp
  // sigma: LDS row r holds K row 32*(r>>5)+8*((r>>2)&3)+4*((r>>4)&1)+(r&3)
  const int rp = (r & 0x23) | ((r & 0x0C) << 1) | ((r & 0x10) >> 2);
  const u16* ksrc = qk + (size_t)(b * 2048 + rp) * 2048 + 1024 + h * 64 + jp * 8;
  const u16* vsrc = vt + (size_t)((b * 16 + h) * 64 + r) * 2048 + jp * 8;
  const size_t ldst = (size_t)(tid & ~63) * 8;

  const f32x4 z4 = {0.f, 0.f, 0.f, 0.f};
  f32x4 o[4];
#pragma unroll
  for (int n = 0; n < 4; ++n) o[n] = z4;
  float mrun = -INFINITY, lrun = 0.f;  // lrun = per-lane PARTIAL (16 kv slots)

  gload16(ksrc, lK[0] + ldst);
  gload16(ksrc + (size_t)32 * 2048, lK[0] + 2048 + ldst);   // sigma(r+32)=sigma(r)+32
  gload16(vsrc, lV[0] + ldst);
  gload16(vsrc + (size_t)32 * 2048, lV[0] + 2048 + ldst);
  __syncthreads();

  int cur = 0;
  for (int t = 0; t <= qt; ++t) {
    if (t < qt) {  // prefetch next K/V tile into the other buffer
      const u16* kn = ksrc + (size_t)(t + 1) * 64 * 2048;
      const u16* vn = vsrc + (size_t)(t + 1) * 64;
      gload16(kn, lK[cur ^ 1] + ldst);
      gload16(kn + (size_t)32 * 2048, lK[cur ^ 1] + 2048 + ldst);
      gload16(vn, lV[cur ^ 1] + ldst);
      gload16(vn + (size_t)32 * 2048, lV[cur ^ 1] + 2048 + ldst);
    }
    // S^T = K Q^T : s[f][j] -> q = r16, kv_true = 32*(f>>1)+8*g+4*(f&1)+j
    f32x4 s[4];
#pragma unroll
    for (int f = 0; f < 4; ++f) s[f] = z4;
    __builtin_amdgcn_s_setprio(1);
#pragma unroll
    for (int kk = 0; kk < 2; ++kk) {
#pragma unroll
      for (int f = 0; f < 4; ++f) {
        int row = f * 16 + r16;
        int off = row * 128 + ((kk * 64 + g * 16) ^ ((r16 & 7) << 4));
        bf16x8 ak = *(const bf16x8*)((const char*)lK[cur] + off);
        s[f] = mfma16(ak, aq[kk], s[f]);  // A = K rows (permuted), B = Q rows
      }
    }
    __builtin_amdgcn_s_setprio(0);
    if (t == qt) {  // diagonal tile: causal mask (kv_true > q)
      const int qrel = w * 16 + r16;
#pragma unroll
      for (int f = 0; f < 4; ++f)
#pragma unroll
        for (int j = 0; j < 4; ++j) {
          int kvt = (f >> 1) * 32 + g * 8 + (f & 1) * 4 + j;
          if (kvt > qrel) s[f][j] = -3.0e38f;
        }
    }
    // in-lane online softmax (exp2 domain), lane owns q-row r16
    float mx = fmaxf(fmaxf(fmaxf(s[0][0], s[0][1]), fmaxf(s[0][2], s[0][3])),
                     fmaxf(fmaxf(s[1][0], s[1][1]), fmaxf(s[1][2], s[1][3])));
    mx = fmaxf(mx, fmaxf(fmaxf(fmaxf(s[2][0], s[2][1]), fmaxf(s[2][2], s[2][3])),
                         fmaxf(fmaxf(s[3][0], s[3][1]), fmaxf(s[3][2], s[3][3]))));
    mx = fmaxf(mx, __shfl_xor(mx, 16));
    mx = fmaxf(mx, __shfl_xor(mx, 32));
    // defer-max (T13): skip the O-rescale unless some row grew past THR=8
    if (!__all(mx - mrun <= 8.0f)) {
      float mnew = fmaxf(mrun, mx);
      float corr = exp2fast(mrun - mnew);
      mrun = mnew;
      lrun *= corr;  // row-uniform corr: partial scaling commutes
      float cj[4];
#pragma unroll
      for (int j = 0; j < 4; ++j) cj[j] = __shfl(corr, g * 4 + j);
#pragma unroll
      for (int n = 0; n < 4; ++n)
#pragma unroll
        for (int j = 0; j < 4; ++j) o[n][j] *= cj[j];
    }
    float sm = 0.f;
#pragma unroll
    for (int f = 0; f < 4; ++f)
#pragma unroll
      for (int j = 0; j < 4; ++j) {
        s[f][j] = exp2fast(s[f][j] - mrun);
        sm += s[f][j];
      }
    lrun += sm;  // per-lane partial; row-reduced once in epilogue

    // pack P in-register with native casts (v_cvt): ap[ks] covers
    // kv_true ks*32+g*8+{0..7} = s[2ks][0..3], s[2ks+1][0..3]
    bf16x8 ap0, ap1;
#pragma unroll
    for (int j = 0; j < 4; ++j) {
      ap0[j]     = (__bf16)s[0][j];
      ap0[j + 4] = (__bf16)s[1][j];
      ap1[j]     = (__bf16)s[2][j];
      ap1[j + 4] = (__bf16)s[3][j];
    }
    // PV: A = P (regs), B = V^T rows (d)
    __builtin_amdgcn_s_setprio(1);
#pragma unroll
    for (int n = 0; n < 4; ++n) {
      int row = n * 16 + r16;
      int off0 = row * 128 + ((g * 16) ^ ((r16 & 7) << 4));
      int off1 = row * 128 + ((64 + g * 16) ^ ((r16 & 7) << 4));
      bf16x8 bv0 = *(const bf16x8*)((const char*)lV[cur] + off0);
      o[n] = mfma16(ap0, bv0, o[n]);
      bf16x8 bv1 = *(const bf16x8*)((const char*)lV[cur] + off1);
      o[n] = mfma16(ap1, bv1, o[n]);
    }
    __builtin_amdgcn_s_setprio(0);
    __syncthreads();  // drains prefetch + protects buffer swap
    cur ^= 1;
  }
  // epilogue: row-reduce lrun, then O rows = q = g*4+j, cols = d = n*16+r16
  float lt = lrun;
  lt += __shfl_xor(lt, 16);
  lt += __shfl_xor(lt, 32);
  float lj[4];
#pragma unroll
  for (int j = 0; j < 4; ++j) lj[j] = __shfl(lt, g * 4 + j);
#pragma unroll
  for (int n = 0; n < 4; ++n) {
    int col = h * 64 + n * 16 + r16;
#pragma unroll
    for (int j = 0; j < 4; ++j) {
      int row = b * 2048 + q0w + g * 4 + j;
      ao[(size_t)row * 1024 + col] = f2bf_fast(o[n][j] * (1.f / lj[j]));
    }
  }
}

// ---------------- launch ----------------

extern "C" void kernel_launch(void* const* d_in, const int* in_sizes, int n_in,
                              void* d_out, int out_size, void* d_ws, size_t ws_size,
                              hipStream_t stream) {
  const float* x     = (const float*)d_in[0];
  // d_in[1] = attn_mask: causal tril, implemented analytically — unused.
  const float* w_qkv = (const float*)d_in[2];
  const float* w_out = (const float*)d_in[3];
  float* out = (float*)d_out;

  u16* ws = (u16*)d_ws;
  u16* x_bf  = ws;                               // 4096*1024  (4M)
  u16* wqkvT = x_bf + (size_t)4096 * 1024;       // 3072*1024  (3M)
  u16* woutT = wqkvT + (size_t)3072 * 1024;      // 1024*1024  (1M)
  u16* qk    = woutT + (size_t)1024 * 1024;      // 4096*2048  (8M)
  u16* vtb   = qk + (size_t)4096 * 2048;         // 2048*2048  (4M)
  u16* ao    = vtb + (size_t)2048 * 2048;        // 4096*1024  (4M)

  prep<<<5120, 256, 0, stream>>>(x, w_qkv, w_out, x_bf, wqkvT, woutT);
  gemm_bf16<<<768, 256, 0, stream>>>(x_bf, wqkvT, qk, vtb, 24, 96);
  attn_fused<<<1024, 256, 0, stream>>>(qk, vtb, ao);
  gemm64<<<1024, 256, 0, stream>>>(ao, woutT, out, 1024, 16, 128);
}

// Round 12
// 190.375 us; speedup vs baseline: 1.0436x; 1.0125x over previous
//
#include <hip/hip_runtime.h>
#include <hip/hip_bf16.h>

// B=2, N=2048, D=1024, H=16, DH=64. f32 in / f32 out, bf16 MFMA internally.

typedef unsigned short u16;
typedef unsigned int u32;
typedef __bf16 bf16x8 __attribute__((ext_vector_type(8)));
typedef float  f32x4  __attribute__((ext_vector_type(4)));
typedef unsigned short u16x4 __attribute__((ext_vector_type(4)));

#define DEV __device__ __forceinline__

DEV float exp2fast(float x) { return __builtin_amdgcn_exp2f(x); }  // v_exp_f32

DEV u16 f2bf(float f) {  // RNE, used in prep/gemm epilogues
  unsigned u = __builtin_bit_cast(unsigned, f);
  return (u16)((u + 0x7FFFu + ((u >> 16) & 1u)) >> 16);
}

DEV u16 f2bf_fast(float f) {  // native cast -> v_cvt (attn hot path)
  __bf16 h = (__bf16)f;
  return __builtin_bit_cast(u16, h);
}

DEV f32x4 mfma16(bf16x8 a, bf16x8 b, f32x4 c) {
  return __builtin_amdgcn_mfma_f32_16x16x32_bf16(a, b, c, 0, 0, 0);
}

template <typename T>
DEV void gload16(const T* g, T* l) {  // global -> LDS, 16B per lane, dest = base + lane*16
  __builtin_amdgcn_global_load_lds((__attribute__((address_space(1))) void*)g,
                                   (__attribute__((address_space(3))) void*)l, 16, 0, 0);
}

// ---------------- merged prep: x-convert + both weight transposes ----------

__global__ __launch_bounds__(256) void prep(const float* __restrict__ x,
                                            const float* __restrict__ wq,
                                            const float* __restrict__ wo,
                                            u16* __restrict__ xb,
                                            u16* __restrict__ dq,
                                            u16* __restrict__ dow) {
  __shared__ u16 T[64][72];
  const int tid = threadIdx.x;
  const int id = (int)blockIdx.x;
  if (id < 4096) {  // x f32 -> bf16, 1024 elems/block
    int idx = (id * 256 + tid) * 4;
    float4 v = *(const float4*)(x + idx);
    u16x4 u = { f2bf(v.x), f2bf(v.y), f2bf(v.z), f2bf(v.w) };
    *(u16x4*)(xb + idx) = u;
    return;
  }
  int wid = id - 4096;                  // [0, 1024)
  int bx = wid & 63, by = wid >> 6;     // 64 x 16 tiles
  const float* src; u16* dst; int C, sl;
  if (bx < 48) { src = wq; dst = dq; C = 3072; sl = 1024; }
  else         { bx -= 48; src = wo; dst = dow; C = 1024; sl = 0; }
  const int c0 = bx * 64, r0 = by * 64;
  const int cl = tid & 63;
  // q-scale folded: 1/sqrt(64) * log2(e)  (softmax runs in exp2 domain)
  const float scale = (c0 + cl < sl) ? 0.125f * 1.4426950408889634f : 1.0f;
#pragma unroll
  for (int i = 0; i < 16; ++i) {
    int r = (tid >> 6) * 16 + i;
    T[cl][r] = f2bf(src[(size_t)(r0 + r) * C + c0 + cl] * scale);
  }
  __syncthreads();
#pragma unroll
  for (int i = 0; i < 16; ++i) {
    int cc = (tid >> 6) * 16 + i;
    dst[(size_t)(c0 + cc) * 1024 + r0 + cl] = T[cc][cl];
  }
}

// ---------------- GEMM1: [4096,1024] x [3072,1024]^T, 128x128 tile ----------
// NOW double-buffered: next K-tile's gload_lds issued BEFORE compute, single
// end-of-iteration barrier drains (attn-proven pattern). LDS 64KB, 2 blk/CU.
// Q/K cols (n0<2048) -> qk[row][2048]; V cols -> vt[b][h][d][n] directly.

__global__ __launch_bounds__(256) void gemm_bf16(const u16* __restrict__ A,
                                                 const u16* __restrict__ Bt,
                                                 u16* __restrict__ qk,
                                                 u16* __restrict__ vt,
                                                 int nx, int cpx) {
  __shared__ __align__(16) u16 lA[2][128 * 64];
  __shared__ __align__(16) u16 lB[2][128 * 64];
  const int tid = threadIdx.x;
  const int lane = tid & 63, w = tid >> 6;
  const int g = lane >> 4, r16 = lane & 15;
  const int wm = w >> 1, wn = w & 1;
  const int id = (int)blockIdx.x;
  const int newid = (id & 7) * cpx + (id >> 3);  // nwg % 8 == 0
  const int m0 = (newid / nx) * 128, n0 = (newid % nx) * 128;

  // staging decomposition (fixed per thread)
  const int sr[4] = { tid >> 3, (256 + tid) >> 3, (512 + tid) >> 3, (768 + tid) >> 3 };
  int sjp[4];
#pragma unroll
  for (int is = 0; is < 4; ++is) sjp[is] = ((is * 256 + tid) & 7) ^ (sr[is] & 7);
  const size_t sdst[4] = { (size_t)(tid & ~63) * 8, (size_t)(256 + (tid & ~63)) * 8,
                           (size_t)(512 + (tid & ~63)) * 8, (size_t)(768 + (tid & ~63)) * 8 };

  const f32x4 z4 = {0.f, 0.f, 0.f, 0.f};
  f32x4 acc[4][4];
#pragma unroll
  for (int m = 0; m < 4; ++m)
#pragma unroll
    for (int n = 0; n < 4; ++n) acc[m][n] = z4;

  // prologue: stage K-tile 0 into buffer 0
#pragma unroll
  for (int is = 0; is < 4; ++is) {
    gload16(A + (size_t)(m0 + sr[is]) * 1024 + sjp[is] * 8, lA[0] + sdst[is]);
    gload16(Bt + (size_t)(n0 + sr[is]) * 1024 + sjp[is] * 8, lB[0] + sdst[is]);
  }
  __syncthreads();

  int cur = 0;
  for (int kt = 0; kt < 16; ++kt) {
    if (kt < 15) {  // prefetch next K-tile into the other buffer
      const int kb = (kt + 1) * 64;
#pragma unroll
      for (int is = 0; is < 4; ++is) {
        gload16(A + (size_t)(m0 + sr[is]) * 1024 + kb + sjp[is] * 8, lA[cur ^ 1] + sdst[is]);
        gload16(Bt + (size_t)(n0 + sr[is]) * 1024 + kb + sjp[is] * 8, lB[cur ^ 1] + sdst[is]);
      }
    }
#pragma unroll
    for (int kk = 0; kk < 2; ++kk) {
      bf16x8 a[4], b[4];
#pragma unroll
      for (int m = 0; m < 4; ++m) {
        int row = wm * 64 + m * 16 + r16;
        int off = row * 128 + ((kk * 64 + g * 16) ^ ((r16 & 7) << 4));
        a[m] = *(const bf16x8*)((const char*)lA[cur] + off);
      }
#pragma unroll
      for (int n = 0; n < 4; ++n) {
        int row = wn * 64 + n * 16 + r16;
        int off = row * 128 + ((kk * 64 + g * 16) ^ ((r16 & 7) << 4));
        b[n] = *(const bf16x8*)((const char*)lB[cur] + off);
      }
      __builtin_amdgcn_s_setprio(1);
#pragma unroll
      for (int m = 0; m < 4; ++m)
#pragma unroll
        for (int n = 0; n < 4; ++n) acc[m][n] = mfma16(a[m], b[n], acc[m][n]);
      __builtin_amdgcn_s_setprio(0);
    }
    __syncthreads();  // drains prefetch + protects buffer swap
    cur ^= 1;
  }
  if (n0 < 2048) {  // Q/K -> qk[row][2048]
#pragma unroll
    for (int m = 0; m < 4; ++m)
#pragma unroll
      for (int n = 0; n < 4; ++n) {
        int col = n0 + wn * 64 + n * 16 + r16;
#pragma unroll
        for (int j = 0; j < 4; ++j) {
          int row = m0 + wm * 64 + m * 16 + g * 4 + j;
          qk[(size_t)row * 2048 + col] = f2bf(acc[m][n][j]);
        }
      }
  } else {  // V -> vt[(b*16+h)*64+d][2048] packed 4-row u16x4 stores
#pragma unroll
    for (int m = 0; m < 4; ++m) {
      int row0 = m0 + wm * 64 + m * 16 + g * 4;  // j = 0..3 consecutive rows
      int b = row0 >> 11, nn0 = row0 & 2047;
#pragma unroll
      for (int n = 0; n < 4; ++n) {
        int hcol = n0 - 2048 + wn * 64 + n * 16 + r16;
        int h = hcol >> 6, d = hcol & 63;
        u16x4 pk = { f2bf(acc[m][n][0]), f2bf(acc[m][n][1]),
                     f2bf(acc[m][n][2]), f2bf(acc[m][n][3]) };
        *(u16x4*)(vt + (size_t)((b * 16 + h) * 64 + d) * 2048 + nn0) = pk;
      }
    }
  }
}

// ---------------- GEMM2: [4096,1024] x [1024,1024]^T, 128x64 tile -----------
// grid 512 = exactly 2 blocks/CU resident (no queuing); prefetch dbuf.

__global__ __launch_bounds__(256) void gemm_out(const u16* __restrict__ A,
                                                const u16* __restrict__ Bt,
                                                float* __restrict__ Cf,
                                                int nx, int cpx) {
  __shared__ __align__(16) u16 lA[2][128 * 64];
  __shared__ __align__(16) u16 lB[2][64 * 64];
  const int tid = threadIdx.x;
  const int lane = tid & 63, w = tid >> 6;
  const int g = lane >> 4, r16 = lane & 15;
  const int wm = w >> 1, wn = w & 1;
  const int id = (int)blockIdx.x;
  const int newid = (id & 7) * cpx + (id >> 3);
  const int m0 = (newid / nx) * 128, n0 = (newid % nx) * 64;

  const int sr[4] = { tid >> 3, (256 + tid) >> 3, (512 + tid) >> 3, (768 + tid) >> 3 };
  int sjp[4];
#pragma unroll
  for (int is = 0; is < 4; ++is) sjp[is] = ((is * 256 + tid) & 7) ^ (sr[is] & 7);
  const size_t sdst[4] = { (size_t)(tid & ~63) * 8, (size_t)(256 + (tid & ~63)) * 8,
                           (size_t)(512 + (tid & ~63)) * 8, (size_t)(768 + (tid & ~63)) * 8 };

  const f32x4 z4 = {0.f, 0.f, 0.f, 0.f};
  f32x4 acc[4][2];
#pragma unroll
  for (int m = 0; m < 4; ++m)
#pragma unroll
    for (int n = 0; n < 2; ++n) acc[m][n] = z4;

  // prologue: stage K-tile 0 (A: 4 issues, B: 2 issues)
#pragma unroll
  for (int is = 0; is < 4; ++is)
    gload16(A + (size_t)(m0 + sr[is]) * 1024 + sjp[is] * 8, lA[0] + sdst[is]);
#pragma unroll
  for (int is = 0; is < 2; ++is)
    gload16(Bt + (size_t)(n0 + sr[is]) * 1024 + sjp[is] * 8, lB[0] + sdst[is]);
  __syncthreads();

  int cur = 0;
  for (int kt = 0; kt < 16; ++kt) {
    if (kt < 15) {
      const int kb = (kt + 1) * 64;
#pragma unroll
      for (int is = 0; is < 4; ++is)
        gload16(A + (size_t)(m0 + sr[is]) * 1024 + kb + sjp[is] * 8, lA[cur ^ 1] + sdst[is]);
#pragma unroll
      for (int is = 0; is < 2; ++is)
        gload16(Bt + (size_t)(n0 + sr[is]) * 1024 + kb + sjp[is] * 8, lB[cur ^ 1] + sdst[is]);
    }
#pragma unroll
    for (int kk = 0; kk < 2; ++kk) {
      bf16x8 a[4], b[2];
#pragma unroll
      for (int m = 0; m < 4; ++m) {
        int row = wm * 64 + m * 16 + r16;
        int off = row * 128 + ((kk * 64 + g * 16) ^ ((r16 & 7) << 4));
        a[m] = *(const bf16x8*)((const char*)lA[cur] + off);
      }
#pragma unroll
      for (int n = 0; n < 2; ++n) {
        int row = wn * 32 + n * 16 + r16;
        int off = row * 128 + ((kk * 64 + g * 16) ^ ((r16 & 7) << 4));
        b[n] = *(const bf16x8*)((const char*)lB[cur] + off);
      }
      __builtin_amdgcn_s_setprio(1);
#pragma unroll
      for (int m = 0; m < 4; ++m)
#pragma unroll
        for (int n = 0; n < 2; ++n) acc[m][n] = mfma16(a[m], b[n], acc[m][n]);
      __builtin_amdgcn_s_setprio(0);
    }
    __syncthreads();
    cur ^= 1;
  }
#pragma unroll
  for (int m = 0; m < 4; ++m)
#pragma unroll
    for (int n = 0; n < 2; ++n) {
      int col = n0 + wn * 32 + n * 16 + r16;
#pragma unroll
      for (int j = 0; j < 4; ++j) {
        int row = m0 + wm * 64 + m * 16 + g * 4 + j;
        Cf[(size_t)row * 1024 + col] = acc[m][n][j];
      }
    }
}

// ---------------- fused causal flash attention (unchanged from R9/R11) ------

__global__ __launch_bounds__(256) void attn_fused(const u16* __restrict__ qk,
                                                  const u16* __restrict__ vt,
                                                  u16* __restrict__ ao) {
  __shared__ __align__(16) u16 lK[2][64 * 64];
  __shared__ __align__(16) u16 lV[2][64 * 64];
  const int tid = threadIdx.x;
  const int lane = tid & 63, w = tid >> 6;
  const int g = lane >> 4, r16 = lane & 15;

  const int flat = (int)blockIdx.x;
  const int xcd = flat & 7;
  const int cu = (flat >> 3) & 31;
  const int round = (flat >> 8) & 3;
  const int grp = xcd * 4 + round;               // b*16+h
  const int qt = (round < 2) ? (31 - cu) : cu;
  const int b = grp >> 4, h = grp & 15;
  const int q0w = qt * 64 + w * 16;

  bf16x8 aq[2];
  {
    const u16* qrow = qk + (size_t)(b * 2048 + q0w + r16) * 2048 + h * 64;
    aq[0] = *(const bf16x8*)(qrow + g * 8);
    aq[1] = *(const bf16x8*)(qrow + 32 + g * 8);
  }

  const int r = tid >> 3, jp = (tid & 7) ^ (r & 7);
  const int rp = (r & 0x23) | ((r & 0x0C) << 1) | ((r & 0x10) >> 2);
  const u16* ksrc = qk + (size_t)(b * 2048 + rp) * 2048 + 1024 + h * 64 + jp * 8;
  const u16* vsrc = vt + (size_t)((b * 16 + h) * 64 + r) * 2048 + jp * 8;
  const size_t ldst = (size_t)(tid & ~63) * 8;

  const f32x4 z4 = {0.f, 0.f, 0.f, 0.f};
  f32x4 o[4];
#pragma unroll
  for (int n = 0; n < 4; ++n) o[n] = z4;
  float mrun = -INFINITY, lrun = 0.f;

  gload16(ksrc, lK[0] + ldst);
  gload16(ksrc + (size_t)32 * 2048, lK[0] + 2048 + ldst);
  gload16(vsrc, lV[0] + ldst);
  gload16(vsrc + (size_t)32 * 2048, lV[0] + 2048 + ldst);
  __syncthreads();

  int cur = 0;
  for (int t = 0; t <= qt; ++t) {
    if (t < qt) {
      const u16* kn = ksrc + (size_t)(t + 1) * 64 * 2048;
      const u16* vn = vsrc + (size_t)(t + 1) * 64;
      gload16(kn, lK[cur ^ 1] + ldst);
      gload16(kn + (size_t)32 * 2048, lK[cur ^ 1] + 2048 + ldst);
      gload16(vn, lV[cur ^ 1] + ldst);
      gload16(vn + (size_t)32 * 2048, lV[cur ^ 1] + 2048 + ldst);
    }
    f32x4 s[4];
#pragma unroll
    for (int f = 0; f < 4; ++f) s[f] = z4;
    __builtin_amdgcn_s_setprio(1);
#pragma unroll
    for (int kk = 0; kk < 2; ++kk) {
#pragma unroll
      for (int f = 0; f < 4; ++f) {
        int row = f * 16 + r16;
        int off = row * 128 + ((kk * 64 + g * 16) ^ ((r16 & 7) << 4));
        bf16x8 ak = *(const bf16x8*)((const char*)lK[cur] + off);
        s[f] = mfma16(ak, aq[kk], s[f]);
      }
    }
    __builtin_amdgcn_s_setprio(0);
    if (t == qt) {
      const int qrel = w * 16 + r16;
#pragma unroll
      for (int f = 0; f < 4; ++f)
#pragma unroll
        for (int j = 0; j < 4; ++j) {
          int kvt = (f >> 1) * 32 + g * 8 + (f & 1) * 4 + j;
          if (kvt > qrel) s[f][j] = -3.0e38f;
        }
    }
    float mx = fmaxf(fmaxf(fmaxf(s[0][0], s[0][1]), fmaxf(s[0][2], s[0][3])),
                     fmaxf(fmaxf(s[1][0], s[1][1]), fmaxf(s[1][2], s[1][3])));
    mx = fmaxf(mx, fmaxf(fmaxf(fmaxf(s[2][0], s[2][1]), fmaxf(s[2][2], s[2][3])),
                         fmaxf(fmaxf(s[3][0], s[3][1]), fmaxf(s[3][2], s[3][3]))));
    mx = fmaxf(mx, __shfl_xor(mx, 16));
    mx = fmaxf(mx, __shfl_xor(mx, 32));
    if (!__all(mx - mrun <= 8.0f)) {
      float mnew = fmaxf(mrun, mx);
      float corr = exp2fast(mrun - mnew);
      mrun = mnew;
      lrun *= corr;
      float cj[4];
#pragma unroll
      for (int j = 0; j < 4; ++j) cj[j] = __shfl(corr, g * 4 + j);
#pragma unroll
      for (int n = 0; n < 4; ++n)
#pragma unroll
        for (int j = 0; j < 4; ++j) o[n][j] *= cj[j];
    }
    float sm = 0.f;
#pragma unroll
    for (int f = 0; f < 4; ++f)
#pragma unroll
      for (int j = 0; j < 4; ++j) {
        s[f][j] = exp2fast(s[f][j] - mrun);
        sm += s[f][j];
      }
    lrun += sm;

    bf16x8 ap0, ap1;
#pragma unroll
    for (int j = 0; j < 4; ++j) {
      ap0[j]     = (__bf16)s[0][j];
      ap0[j + 4] = (__bf16)s[1][j];
      ap1[j]     = (__bf16)s[2][j];
      ap1[j + 4] = (__bf16)s[3][j];
    }
    __builtin_amdgcn_s_setprio(1);
#pragma unroll
    for (int n = 0; n < 4; ++n) {
      int row = n * 16 + r16;
      int off0 = row * 128 + ((g * 16) ^ ((r16 & 7) << 4));
      int off1 = row * 128 + ((64 + g * 16) ^ ((r16 & 7) << 4));
      bf16x8 bv0 = *(const bf16x8*)((const char*)lV[cur] + off0);
      o[n] = mfma16(ap0, bv0, o[n]);
      bf16x8 bv1 = *(const bf16x8*)((const char*)lV[cur] + off1);
      o[n] = mfma16(ap1, bv1, o[n]);
    }
    __builtin_amdgcn_s_setprio(0);
    __syncthreads();
    cur ^= 1;
  }
  float lt = lrun;
  lt += __shfl_xor(lt, 16);
  lt += __shfl_xor(lt, 32);
  float lj[4];
#pragma unroll
  for (int j = 0; j < 4; ++j) lj[j] = __shfl(lt, g * 4 + j);
#pragma unroll
  for (int n = 0; n < 4; ++n) {
    int col = h * 64 + n * 16 + r16;
#pragma unroll
    for (int j = 0; j < 4; ++j) {
      int row = b * 2048 + q0w + g * 4 + j;
      ao[(size_t)row * 1024 + col] = f2bf_fast(o[n][j] * (1.f / lj[j]));
    }
  }
}

// ---------------- launch ----------------

extern "C" void kernel_launch(void* const* d_in, const int* in_sizes, int n_in,
                              void* d_out, int out_size, void* d_ws, size_t ws_size,
                              hipStream_t stream) {
  const float* x     = (const float*)d_in[0];
  // d_in[1] = attn_mask: causal tril, implemented analytically — unused.
  const float* w_qkv = (const float*)d_in[2];
  const float* w_out = (const float*)d_in[3];
  float* out = (float*)d_out;

  u16* ws = (u16*)d_ws;
  u16* x_bf  = ws;                               // 4096*1024  (4M)
  u16* wqkvT = x_bf + (size_t)4096 * 1024;       // 3072*1024  (3M)
  u16* woutT = wqkvT + (size_t)3072 * 1024;      // 1024*1024  (1M)
  u16* qk    = woutT + (size_t)1024 * 1024;      // 4096*2048  (8M)
  u16* vtb   = qk + (size_t)4096 * 2048;         // 2048*2048  (4M)
  u16* ao    = vtb + (size_t)2048 * 2048;        // 4096*1024  (4M)

  prep<<<5120, 256, 0, stream>>>(x, w_qkv, w_out, x_bf, wqkvT, woutT);
  gemm_bf16<<<768, 256, 0, stream>>>(x_bf, wqkvT, qk, vtb, 24, 96);
  attn_fused<<<1024, 256, 0, stream>>>(qk, vtb, ao);
  gemm_out<<<512, 256, 0, stream>>>(ao, woutT, out, 16, 64);
}